// Round 12
// baseline (344.881 us; speedup 1.0000x reference)
//
#include <hip/hip_runtime.h>
#include <cmath>

// ---- problem constants ----
#define DIMC   256
#define L_WIN  1023        // (131072-256)/128 + 1
#define M_VALID 4092       // 4*1023 tokens
#define M_PAD  4096
#define DI     1024        // D_INNER
#define TLEN   131072
#define SEG    32          // scan segment length
#define NSEG   32          // 32*32 = 1024 >= 1023
#define DTSTRIDE 65536     // 4096*16 elems per dtile plane in perm layouts

typedef __bf16 bf16x8 __attribute__((ext_vector_type(8)));
typedef __bf16 bf16x4 __attribute__((ext_vector_type(4)));
typedef __bf16 bf16x2 __attribute__((ext_vector_type(2)));
typedef float  f32x4  __attribute__((ext_vector_type(4)));

__device__ __forceinline__ float sigmoidf_(float x){ return 1.f/(1.f + __expf(-x)); }
__device__ __forceinline__ float softplusf_(float v){ return fmaxf(v,0.f) + log1pf(__expf(-fabsf(v))); }

// DPP rotate-add: pure-VALU cross-lane sum step (no LDS traffic)
template<int CTRL>
__device__ __forceinline__ float dpp_add(float x){
  int v = __builtin_amdgcn_update_dpp(0, __builtin_bit_cast(int, x), CTRL, 0xF, 0xF, true);
  return x + __builtin_bit_cast(float, v);
}

// ---------------- init: frame (blocks 0..4095) + weight bf16 convert (blocks 4096+) ----------------
__global__ __launch_bounds__(256) void init_kernel(const float* __restrict__ x, float* __restrict__ res,
    const float* __restrict__ a, __bf16* __restrict__ da, int na,
    const float* __restrict__ b, __bf16* __restrict__ db, int nb,
    const float* __restrict__ c, __bf16* __restrict__ dc, int nc)
{
  if (blockIdx.x < M_PAD){
    int m = blockIdx.x, j = threadIdx.x;
    float v = 0.f;
    if (m < M_VALID){
      int bb = m / L_WIN, l = m - bb*L_WIN;
      v = x[(size_t)bb*TLEN + l*128 + j];
    }
    res[(size_t)m*DIMC + j] = v;
    return;
  }
  int nblk = gridDim.x - M_PAD;
  int stride = nblk*256;
  int base = (blockIdx.x - M_PAD)*256 + threadIdx.x;
  for (int i = base; i < na; i += stride) da[i] = (__bf16)a[i];
  for (int i = base; i < nb; i += stride) db[i] = (__bf16)b[i];
  for (int i = base; i < nc; i += stride) dc[i] = (__bf16)c[i];
}

// ---------------- rmsnorm row of 256 -> bf16 ----------------
__global__ __launch_bounds__(256) void rms_kernel(const float* __restrict__ src, __bf16* __restrict__ dst,
                                                  const float* __restrict__ w){
  int m = blockIdx.x, j = threadIdx.x;
  float v = (m < M_VALID) ? src[(size_t)m*DIMC + j] : 0.f;
  float s = v*v;
  #pragma unroll
  for (int off = 32; off; off >>= 1) s += __shfl_down(s, off);
  __shared__ float ls[4];
  if ((threadIdx.x & 63) == 0) ls[threadIdx.x >> 6] = s;
  __syncthreads();
  float tot = ls[0] + ls[1] + ls[2] + ls[3];
  float scale = rsqrtf(tot * (1.f/DIMC) + 1e-5f);
  dst[(size_t)m*DIMC + j] = (__bf16)(v * scale * w[j]);
}

// ======== in_proj LDS-tiled MFMA GEMM: [M x 2048] = hn @ w_in^T, split output ========
// 128x128 tile; blocks with n0<1024 write xc16 [m][1024]; others write z_perm [dtile][m][16].
__global__ __launch_bounds__(256) void gemm_inproj_kernel(const __bf16* __restrict__ A, const __bf16* __restrict__ B,
    __bf16* __restrict__ xc16, __bf16* __restrict__ z_perm)
{
  constexpr int LDK = 72;
  __shared__ __bf16 As[128*LDK];
  __shared__ __bf16 Bs[128*LDK];
  int tid  = threadIdx.x;
  int lane = tid & 63, wv = tid >> 6;
  int row  = lane & 15, kq = lane >> 4;
  int m0 = blockIdx.x*128, n0 = blockIdx.y*128;
  int wmo = (wv >> 1)*64;
  int wno = (wv &  1)*64;
  f32x4 acc[4][4] = {};
  for (int kt = 0; kt < 256; kt += 64){
    __syncthreads();
    #pragma unroll
    for (int r = 0; r < 4; ++r){
      int seg = r*256 + tid;
      int rw = seg >> 3, sb = seg & 7;
      *(bf16x8*)(As + rw*LDK + sb*8) = *(const bf16x8*)(A + (size_t)(m0 + rw)*256 + kt + sb*8);
    }
    #pragma unroll
    for (int r = 0; r < 4; ++r){
      int seg = r*256 + tid;
      int rw = seg >> 3, sb = seg & 7;
      *(bf16x8*)(Bs + rw*LDK + sb*8) = *(const bf16x8*)(B + (size_t)(n0 + rw)*256 + kt + sb*8);
    }
    __syncthreads();
    #pragma unroll
    for (int ks = 0; ks < 2; ++ks){
      bf16x8 af[4], bfr[4];
      #pragma unroll
      for (int i = 0; i < 4; ++i) af[i]  = *(const bf16x8*)(As + (wmo + i*16 + row)*LDK + ks*32 + kq*8);
      #pragma unroll
      for (int j = 0; j < 4; ++j) bfr[j] = *(const bf16x8*)(Bs + (wno + j*16 + row)*LDK + ks*32 + kq*8);
      #pragma unroll
      for (int i = 0; i < 4; ++i){
        #pragma unroll
        for (int j = 0; j < 4; ++j)
          acc[i][j] = __builtin_amdgcn_mfma_f32_16x16x32_bf16(af[i], bfr[j], acc[i][j], 0, 0, 0);
      }
    }
  }
  bool isz = (n0 >= 1024);
  #pragma unroll
  for (int i = 0; i < 4; ++i){
    int cm = m0 + wmo + i*16 + kq*4;
    #pragma unroll
    for (int j = 0; j < 4; ++j){
      int cn = n0 + wno + j*16 + row;
      #pragma unroll
      for (int ii = 0; ii < 4; ++ii){
        __bf16 bv = (__bf16)acc[i][j][ii];
        if (!isz){
          xc16[(size_t)(cm + ii)*1024 + cn] = bv;
        } else {
          int zn = cn - 1024;
          z_perm[(size_t)(zn >> 4)*DTSTRIDE + (size_t)(cm + ii)*16 + (zn & 15)] = bv;
        }
      }
    }
  }
}

// ======== out_proj LDS-tiled MFMA GEMM (generic, f32 out + in-place residual) ========
__global__ __launch_bounds__(256) void gemm_outproj_kernel(const __bf16* __restrict__ A, const __bf16* __restrict__ B,
    float* C, int K, int ldc)
{
  constexpr int LDK = 72;
  __shared__ __bf16 As[64*LDK];
  __shared__ __bf16 Bs[64*LDK];
  int tid  = threadIdx.x;
  int lane = tid & 63, wv = tid >> 6;
  int row  = lane & 15, kq = lane >> 4;
  int m0 = blockIdx.x*64, n0 = blockIdx.y*64;
  int wmo = (wv >> 1)*32;
  int wno = (wv &  1)*32;
  f32x4 acc[2][2] = {};
  for (int kt = 0; kt < K; kt += 64){
    __syncthreads();
    #pragma unroll
    for (int r = 0; r < 2; ++r){
      int seg = r*256 + tid;
      int rw = seg >> 3, sb = seg & 7;
      *(bf16x8*)(As + rw*LDK + sb*8) = *(const bf16x8*)(A + (size_t)(m0 + rw)*K + kt + sb*8);
    }
    #pragma unroll
    for (int r = 0; r < 2; ++r){
      int seg = r*256 + tid;
      int rw = seg >> 3, sb = seg & 7;
      *(bf16x8*)(Bs + rw*LDK + sb*8) = *(const bf16x8*)(B + (size_t)(n0 + rw)*K + kt + sb*8);
    }
    __syncthreads();
    #pragma unroll
    for (int ks = 0; ks < 2; ++ks){
      bf16x8 af[2], bfr[2];
      #pragma unroll
      for (int i = 0; i < 2; ++i) af[i]  = *(const bf16x8*)(As + (wmo + i*16 + row)*LDK + ks*32 + kq*8);
      #pragma unroll
      for (int j = 0; j < 2; ++j) bfr[j] = *(const bf16x8*)(Bs + (wno + j*16 + row)*LDK + ks*32 + kq*8);
      #pragma unroll
      for (int i = 0; i < 2; ++i){
        #pragma unroll
        for (int j = 0; j < 2; ++j)
          acc[i][j] = __builtin_amdgcn_mfma_f32_16x16x32_bf16(af[i], bfr[j], acc[i][j], 0, 0, 0);
      }
    }
  }
  #pragma unroll
  for (int i = 0; i < 2; ++i){
    int cm = m0 + wmo + i*16 + kq*4;
    #pragma unroll
    for (int j = 0; j < 2; ++j){
      int cn = n0 + wno + j*16 + row;
      #pragma unroll
      for (int ii = 0; ii < 4; ++ii){
        size_t idx = (size_t)(cm + ii)*ldc + cn;
        C[idx] = C[idx] + acc[i][j][ii];   // in-place residual: 1 thread per element
      }
    }
  }
}

// ======== fused conv4+SiLU -> xproj MFMA -> dt_proj+softplus, perm-layout outputs ========
// grid = 256 blocks x 256 thr. Outputs: u_perm/delta_perm [dtile][m][16] bf16,
// BC_perm [m][16] float2 (B,C). Numerics identical to r11 chain.
__global__ __launch_bounds__(256) void conv_xproj_dt_kernel(
  const __bf16* __restrict__ xc16, const float* __restrict__ cw, const float* __restrict__ cb,
  const __bf16* __restrict__ wxp, const float* __restrict__ dtw, const float* __restrict__ dtb,
  __bf16* __restrict__ u_perm, float2* __restrict__ BCp, __bf16* __restrict__ delta_perm)
{
  __shared__ __bf16 su[16][1032];   // +8 pad
  __shared__ float  sdt[16][17];
  int tid = threadIdx.x;
  int m0 = blockIdx.x * 16;
  // ---- phase A: causal depthwise conv4 + bias + SiLU -> su ----
  {
    int d = tid * 4;
    float w[4][4], bias[4];
    #pragma unroll
    for (int c = 0; c < 4; ++c){
      #pragma unroll
      for (int j = 0; j < 4; ++j) w[c][j] = cw[(d + c)*4 + j];
      bias[c] = cb[d + c];
    }
    for (int ti = 0; ti < 16; ++ti){
      int m = m0 + ti;
      float acc[4] = {0.f, 0.f, 0.f, 0.f};
      if (m < M_VALID){
        int b = m / L_WIN;
        int l = m - b*L_WIN;
        #pragma unroll
        for (int c = 0; c < 4; ++c) acc[c] = bias[c];
        #pragma unroll
        for (int k = 0; k < 4; ++k){
          if (l >= k){
            bf16x4 xv = *(const bf16x4*)(xc16 + (size_t)(m - k)*1024 + d);
            #pragma unroll
            for (int c = 0; c < 4; ++c) acc[c] = fmaf((float)xv[c], w[c][3-k], acc[c]);
          }
        }
        #pragma unroll
        for (int c = 0; c < 4; ++c) acc[c] = acc[c] * sigmoidf_(acc[c]);
      }
      bf16x4 o;
      #pragma unroll
      for (int c = 0; c < 4; ++c) o[c] = (__bf16)acc[c];
      *(bf16x4*)(&su[ti][d]) = o;
    }
  }
  __syncthreads();
  // ---- phase A2: write u_perm from su (coalesced 512B runs) ----
  #pragma unroll
  for (int it = 0; it < 4; ++it){
    int idx = it*256 + tid;
    int dtile = idx >> 4, ti = idx & 15;
    const bf16x8* s = (const bf16x8*)(&su[ti][dtile*16]);
    bf16x8* dpp = (bf16x8*)(u_perm + (size_t)dtile*DTSTRIDE + (size_t)(m0 + ti)*16);
    dpp[0] = s[0]; dpp[1] = s[1];
  }
  // ---- phase B: xproj 16x48, K=1024 (3 waves MFMA; reads su only) ----
  {
    int lane = tid & 63, wv = tid >> 6;
    if (wv < 3){
      int row = lane & 15, kq = lane >> 4;
      f32x4 acc = {0.f, 0.f, 0.f, 0.f};
      const __bf16* Bp = wxp + (size_t)(wv*16 + row)*1024 + kq*8;
      for (int k = 0; k < 1024; k += 32){
        bf16x8 a  = *(const bf16x8*)(&su[row][k + kq*8]);
        bf16x8 bb = *(const bf16x8*)(Bp + k);
        acc = __builtin_amdgcn_mfma_f32_16x16x32_bf16(a, bb, acc, 0, 0, 0);
      }
      #pragma unroll
      for (int i = 0; i < 4; ++i){
        int tok = kq*4 + i;
        if (wv == 0) sdt[tok][row] = acc[i];
        else if (wv == 1) BCp[(size_t)(m0 + tok)*16 + row].x = acc[i];
        else              BCp[(size_t)(m0 + tok)*16 + row].y = acc[i];
      }
    }
  }
  __syncthreads();
  // ---- phase C: dt_proj (K=16) + softplus -> delta_perm ----
  {
    int d0 = tid * 4;
    int dtile = tid >> 2, dd = (tid & 3)*4;
    float w[4][16], bias[4];
    #pragma unroll
    for (int c = 0; c < 4; ++c){
      #pragma unroll
      for (int q = 0; q < 16; ++q) w[c][q] = dtw[(d0 + c)*16 + q];
      bias[c] = dtb[d0 + c];
    }
    for (int t = 0; t < 16; ++t){
      float acc[4] = {bias[0], bias[1], bias[2], bias[3]};
      #pragma unroll
      for (int r = 0; r < 16; ++r){
        float dv = sdt[t][r];
        #pragma unroll
        for (int c = 0; c < 4; ++c) acc[c] = fmaf(dv, w[c][r], acc[c]);
      }
      bf16x4 o;
      #pragma unroll
      for (int c = 0; c < 4; ++c) o[c] = (__bf16)softplusf_(acc[c]);
      *(bf16x4*)(delta_perm + (size_t)dtile*DTSTRIDE + (size_t)(m0 + t)*16 + dd) = o;
    }
  }
}

// ================= chunked two-phase selective scan (r9 inner loops, perm staging) =================
__global__ __launch_bounds__(256) void scan_part1_kernel(
  const __bf16* __restrict__ u_perm, const __bf16* __restrict__ delta_perm,
  const float2* __restrict__ BCp, const float* __restrict__ Alog, float2* __restrict__ Pq)
{
  int bid = blockIdx.x;
  int s = bid & 31, dtile = (bid >> 5) & 63, b = bid >> 11;
  int d0 = dtile << 4;
  int tid = threadIdx.x;
  int c = tid >> 4, n = tid & 15;
  float A_dn = -__expf(Alog[(d0 + c)*16 + n]);
  __shared__ float2 sdd[16][SEG+2];   // (dlt, dlt*u)
  __shared__ float  sB [SEG][17];
  int t0 = s*SEG;
  int nt = L_WIN - t0; if (nt > SEG) nt = SEG;
  size_t base_m = (size_t)b*L_WIN + t0;
  {
    int tt = tid >> 3, nn = (tid & 7)*2;
    float dl0=0.f, dl1=0.f, du0=0.f, du1=0.f, B0=0.f, B1=0.f;
    if (tt < nt){
      size_t mrow = base_m + tt;
      bf16x2 d2 = *(const bf16x2*)(delta_perm + (size_t)dtile*DTSTRIDE + mrow*16 + nn);
      bf16x2 u2 = *(const bf16x2*)(u_perm     + (size_t)dtile*DTSTRIDE + mrow*16 + nn);
      f32x4 bc  = *(const f32x4*)(BCp + mrow*16 + nn);
      dl0 = (float)d2[0]; dl1 = (float)d2[1];
      du0 = dl0*(float)u2[0]; du1 = dl1*(float)u2[1];
      B0 = bc.x; B1 = bc.z;
    }
    sdd[nn][tt]   = make_float2(dl0, du0);
    sdd[nn+1][tt] = make_float2(dl1, du1);
    sB[tt][nn] = B0; sB[tt][nn+1] = B1;
  }
  __syncthreads();
  float h = 0.f, P = 1.f;
  #pragma unroll 8
  for (int t = 0; t < SEG; ++t){
    float2 dd2 = sdd[c][t];
    float dA = __expf(dd2.x * A_dn);
    h = fmaf(dA, h, dd2.y * sB[t][n]);
    P *= dA;
  }
  Pq[(((size_t)b*NSEG + s) << 14) + d0*16 + tid] = make_float2(P, h);
}

__global__ __launch_bounds__(256) void scan_combine_kernel(const float2* __restrict__ Pq,
                                                           float* __restrict__ hstart)
{
  int idx = blockIdx.x*256 + threadIdx.x;
  int b = idx >> 14;
  int dn = idx & 16383;
  float hs = 0.f;
  #pragma unroll
  for (int s = 0; s < NSEG; ++s){
    size_t o = (((size_t)b*NSEG + s) << 14) + dn;
    hstart[o] = hs;
    float2 pq = Pq[o];
    hs = fmaf(pq.x, hs, pq.y);
  }
}

__global__ __launch_bounds__(256) void scan_part2_kernel(
  const __bf16* __restrict__ u_perm, const __bf16* __restrict__ delta_perm,
  const float2* __restrict__ BCp, const __bf16* __restrict__ z_perm,
  const float* __restrict__ Alog, const float* __restrict__ Dp,
  const float* __restrict__ hstart, __bf16* __restrict__ y16)
{
  int bid = blockIdx.x;
  int s = bid & 31, dtile = (bid >> 5) & 63, b = bid >> 11;
  int d0 = dtile << 4;
  int tid = threadIdx.x;
  int c = tid >> 4, n = tid & 15;
  float A_dn = -__expf(Alog[(d0 + c)*16 + n]);
  __shared__ float2 sdd[16][SEG+2];   // (dlt, u)
  __shared__ float2 sBC[SEG][17];     // (B_n, C_n)
  __shared__ float  sy [16][SEG+1];
  __shared__ float  sD[16];
  if (tid < 16) sD[tid] = Dp[d0 + tid];
  int t0 = s*SEG;
  int nt = L_WIN - t0; if (nt > SEG) nt = SEG;
  size_t base_m = (size_t)b*L_WIN + t0;
  int tt = tid >> 3, nn = (tid & 7)*2;
  {
    float dl0=0.f, dl1=0.f, u0=0.f, u1=0.f;
    f32x4 bc = {0.f, 0.f, 0.f, 0.f};
    if (tt < nt){
      size_t mrow = base_m + tt;
      bf16x2 d2 = *(const bf16x2*)(delta_perm + (size_t)dtile*DTSTRIDE + mrow*16 + nn);
      bf16x2 u2 = *(const bf16x2*)(u_perm     + (size_t)dtile*DTSTRIDE + mrow*16 + nn);
      bc = *(const f32x4*)(BCp + mrow*16 + nn);
      dl0 = (float)d2[0]; dl1 = (float)d2[1];
      u0 = (float)u2[0];  u1 = (float)u2[1];
    }
    sdd[nn][tt]   = make_float2(dl0, u0);
    sdd[nn+1][tt] = make_float2(dl1, u1);
    *(f32x4*)(&sBC[tt][nn]) = bc;     // (B0,C0,B1,C1) -> sBC[tt][nn], sBC[tt][nn+1]
  }
  float h = hstart[(((size_t)b*NSEG + s) << 14) + d0*16 + tid];
  __syncthreads();
  #pragma unroll 8
  for (int t = 0; t < SEG; ++t){
    float2 dd2 = sdd[c][t];
    float dA = __expf(dd2.x * A_dn);
    float2 bc = sBC[t][n];
    h = fmaf(dA, h, dd2.x * dd2.y * bc.x);
    float pp = h * bc.y;
    pp = dpp_add<0xB1>(pp);    // xor1
    pp = dpp_add<0x4E>(pp);    // xor2
    pp = dpp_add<0x141>(pp);   // row_half_mirror
    pp = dpp_add<0x128>(pp);   // row_ror:8
    if (n == 0) sy[c][t] = pp;
  }
  __syncthreads();
  if (tt < nt){
    size_t mrow = base_m + tt;
    bf16x2 z2 = *(const bf16x2*)(z_perm + (size_t)dtile*DTSTRIDE + mrow*16 + nn);
    bf16x2 o;
    #pragma unroll
    for (int c2 = 0; c2 < 2; ++c2){
      int dd = nn + c2;
      float uv = sdd[dd][tt].y;
      float zv = (float)z2[c2];
      float yv = (sy[dd][tt] + uv * sD[dd]) * (zv * sigmoidf_(zv));
      o[c2] = (__bf16)yv;
    }
    *(bf16x2*)(y16 + mrow*DI + d0 + nn) = o;
  }
}

// ---------------- overlap-add fold + passthrough ----------------
__global__ __launch_bounds__(256) void fold_kernel(const float* __restrict__ x, const float* __restrict__ r,
                                                   float* __restrict__ out){
  int i = blockIdx.x*256 + threadIdx.x;
  int b = i >> 17;
  int t = i & (TLEN - 1);
  float acc = x[i];
  int l1 = t >> 7;
  int j  = t & 127;
  if (l1 < L_WIN) acc += r[((size_t)b*L_WIN + l1)*DIMC + j] * ((float)j * (1.f/127.f));
  if (l1 >= 1)    acc += r[((size_t)b*L_WIN + l1 - 1)*DIMC + j + 128] * ((float)(127 - j) * (1.f/127.f));
  out[i] = acc;
}

extern "C" void kernel_launch(void* const* d_in, const int* in_sizes, int n_in,
                              void* d_out, int out_size, void* d_ws, size_t ws_size,
                              hipStream_t stream)
{
  (void)in_sizes; (void)n_in; (void)out_size; (void)ws_size;
  const float* x      = (const float*)d_in[0];
  const float* in_w   = (const float*)d_in[1];
  const float* conv_w = (const float*)d_in[2];
  const float* conv_b = (const float*)d_in[3];
  const float* xp_w   = (const float*)d_in[4];
  const float* dt_w   = (const float*)d_in[5];
  const float* dt_b   = (const float*)d_in[6];
  const float* A_log  = (const float*)d_in[7];
  const float* Dp     = (const float*)d_in[8];
  const float* out_w  = (const float*)d_in[9];
  const float* norm_w = (const float*)d_in[10];
  float* out = (float*)d_out;

  // workspace layout (~75 MB; ws is 256 MiB)
  char* p = (char*)d_ws;
  auto alloc = [&](size_t bytes)->void*{ void* r = (void*)p; p += (bytes + 255) & ~(size_t)255; return r; };
  float*  res     = (float*) alloc((size_t)M_PAD*DIMC*4);         // 4 MB
  __bf16* hn16    = (__bf16*)alloc((size_t)M_PAD*DIMC*2);         // 2 MB
  __bf16* xc16    = (__bf16*)alloc((size_t)M_PAD*1024*2);         // 8 MB
  __bf16* z_perm  = (__bf16*)alloc((size_t)64*DTSTRIDE*2);        // 8 MB
  __bf16* u_perm  = (__bf16*)alloc((size_t)64*DTSTRIDE*2);        // 8 MB
  __bf16* delta_perm = (__bf16*)alloc((size_t)64*DTSTRIDE*2);     // 8 MB
  float2* BCp     = (float2*)alloc((size_t)M_PAD*16*8);           // 0.5 MB
  __bf16* y16     = (__bf16*)alloc((size_t)M_PAD*DI*2);           // 8 MB
  float2* Pq      = (float2*)alloc((size_t)4*NSEG*16384*8);       // 16 MB
  float*  hstart  = (float*) alloc((size_t)4*NSEG*16384*4);       // 8 MB
  __bf16* w_in16  = (__bf16*)alloc((size_t)2*2048*256*2);         // 2 MB
  __bf16* w_xp16  = (__bf16*)alloc((size_t)2*48*1024*2);          // 0.19 MB
  __bf16* w_out16 = (__bf16*)alloc((size_t)2*256*1024*2);         // 1 MB

  init_kernel<<<M_PAD + 512, 256, 0, stream>>>(x, res,
                                               in_w, w_in16, 2*2048*256,
                                               xp_w, w_xp16, 2*48*1024,
                                               out_w, w_out16, 2*256*1024);

  for (int i = 0; i < 2; ++i){
    rms_kernel<<<M_PAD, 256, 0, stream>>>(res, hn16, norm_w + i*256);
    gemm_inproj_kernel<<<dim3(32, 16), 256, 0, stream>>>(hn16, w_in16 + (size_t)i*524288, xc16, z_perm);
    conv_xproj_dt_kernel<<<M_PAD/16, 256, 0, stream>>>(xc16, conv_w + i*4096, conv_b + i*1024,
                                                       w_xp16 + (size_t)i*49152, dt_w + i*16384, dt_b + i*1024,
                                                       u_perm, BCp, delta_perm);
    scan_part1_kernel<<<8192, 256, 0, stream>>>(u_perm, delta_perm, BCp, A_log + i*16384, Pq);
    scan_combine_kernel<<<256, 256, 0, stream>>>(Pq, hstart);
    scan_part2_kernel<<<8192, 256, 0, stream>>>(u_perm, delta_perm, BCp, z_perm, A_log + i*16384, Dp + i*1024,
                                                hstart, y16);
    gemm_outproj_kernel<<<dim3(64, 4), 256, 0, stream>>>(y16, w_out16 + (size_t)i*262144, res, 1024, 256);
  }
  fold_kernel<<<TLEN*4/256, 256, 0, stream>>>(x, res, out);
}